// Round 4
// baseline (451.897 us; speedup 1.0000x reference)
//
#include <hip/hip_runtime.h>
#include <hip/hip_bf16.h>

typedef __bf16 bf16_t;
typedef __attribute__((ext_vector_type(8))) __bf16 bf16x8;
typedef __attribute__((ext_vector_type(4))) float f32x4;

#define MFMA(a, b, c) __builtin_amdgcn_mfma_f32_16x16x32_bf16(a, b, c, 0, 0, 0)

// Async global->LDS, 16B per lane. Dest = wave-uniform base + lane*16 (measured m104).
__device__ inline void gload_lds16(const bf16_t* g, bf16_t* l) {
  __builtin_amdgcn_global_load_lds(
      (const __attribute__((address_space(1))) void*)g,
      (__attribute__((address_space(3))) void*)l, 16, 0, 0);
}

// Diagnostic sentinel (fp32 output): absmax ~= val identifies the guard.
__global__ void fill_sentinel(float* out, int n, float val) {
  int i = blockIdx.x * blockDim.x + threadIdx.x;
  if (i < n) out[i] = val;
}

// Weights fp32 W[h][d][kk] (3 matrices) -> Wt bf16 [m][(h*64+kk)][d]
__global__ void transpose_w(const float* __restrict__ Wq, const float* __restrict__ Wk,
                            const float* __restrict__ Wv, bf16_t* __restrict__ Wt) {
  int gid = blockIdx.x * blockDim.x + threadIdx.x;
  int e = gid * 8;
  int m = e >> 20;
  int rem = e & 1048575;
  int n = rem >> 10;               // h*64+kk
  int d0 = rem & 1023;
  const float* W = (m == 0) ? Wq : (m == 1) ? Wk : Wv;
  int h = n >> 6, kk = n & 63;
  union { bf16_t h8[8]; uint4 u; } tmp;
#pragma unroll
  for (int j = 0; j < 8; ++j)
    tmp.h8[j] = (bf16_t)W[((size_t)(h * 1024 + d0 + j)) * 64 + kk];
  *(uint4*)(Wt + e) = tmp.u;
}

// Vectorized fp32 -> bf16 cast, 8 elems/thread, exact grid (no bounds check).
__global__ void cvt_bf16(const float* __restrict__ in, bf16_t* __restrict__ out) {
  size_t i = (size_t)(blockIdx.x * blockDim.x + threadIdx.x) * 8;
  f32x4 a = *(const f32x4*)(in + i);
  f32x4 b = *(const f32x4*)(in + i + 4);
  bf16x8 r;
  r[0] = (bf16_t)a[0]; r[1] = (bf16_t)a[1]; r[2] = (bf16_t)a[2]; r[3] = (bf16_t)a[3];
  r[4] = (bf16_t)b[0]; r[5] = (bf16_t)b[1]; r[6] = (bf16_t)b[2]; r[7] = (bf16_t)b[3];
  *(bf16x8*)(out + i) = r;
}

// C = A[M,K] * Bt[N,K]^T, all-bf16 inputs, m97-style global_load_lds staging.
// MODE 0: out bf16 [h][b][s][dk]; MODE 1: out bf16 [h][b][dk][s];
// MODE 2: out fp32 [M,N] + bias.  scale applied in MODE 0/1 epilogue.
template <int MODE>
__global__ void gemm_bt(const bf16_t* __restrict__ A, const bf16_t* __restrict__ Bt,
                        const float* __restrict__ bias, void* __restrict__ out_,
                        int M, int N, int K, float scale) {
  // Linear LDS (global_load_lds requires contiguous dest): [128 rows][32 elems].
  __shared__ bf16_t sA[128 * 32];
  __shared__ bf16_t sB[128 * 32];
  const int t = threadIdx.x;
  const int w = t >> 6, l = t & 63;
  const int lq = l >> 4, ll = l & 15;
  const int m0 = blockIdx.x * 128, n0 = blockIdx.y * 128;
  const int wr = (w >> 1) * 64, wc = (w & 1) * 64;
  // Staging: chunk ch = w*2+c covers rows [ch*16, ch*16+16); lane l lands at
  // chunk_base + l*16B -> row = ch*16 + l/4, col = (l&3)*8 elems.
  const int srow = l >> 2;
  const int scol = (l & 3) * 8;
  f32x4 acc[4][4] = {};
  for (int k0 = 0; k0 < K; k0 += 32) {
    __syncthreads();   // prior ds_reads done before overwrite
#pragma unroll
    for (int c = 0; c < 2; ++c) {
      int ch = w * 2 + c;
      int row = ch * 16 + srow;
      gload_lds16(A  + (size_t)(m0 + row) * K + k0 + scol, sA + ch * 512);
      gload_lds16(Bt + (size_t)(n0 + row) * K + k0 + scol, sB + ch * 512);
    }
    __syncthreads();   // implicit vmcnt(0) drains global_load_lds
    bf16x8 af[4], bfr[4];
#pragma unroll
    for (int i = 0; i < 4; ++i) {
      af[i]  = *(const bf16x8*)(sA + (wr + i * 16 + ll) * 32 + lq * 8);
      bfr[i] = *(const bf16x8*)(sB + (wc + i * 16 + ll) * 32 + lq * 8);
    }
#pragma unroll
    for (int mi = 0; mi < 4; ++mi)
#pragma unroll
      for (int ni = 0; ni < 4; ++ni)
        acc[mi][ni] = MFMA(af[mi], bfr[ni], acc[mi][ni]);
  }
  // D layout: col=lane&15, row=(lane>>4)*4+reg (measured m89/m91).
#pragma unroll
  for (int mi = 0; mi < 4; ++mi)
#pragma unroll
    for (int ni = 0; ni < 4; ++ni)
#pragma unroll
      for (int r = 0; r < 4; ++r) {
        int row = m0 + wr + mi * 16 + lq * 4 + r;
        int col = n0 + wc + ni * 16 + ll;
        float v = acc[mi][ni][r];
        if (MODE == 2) {
          ((float*)out_)[(size_t)row * N + col] = v + bias[col];
        } else {
          int h = col >> 6, kk = col & 63, b = row >> 10, s = row & 1023;
          size_t idx;
          if (MODE == 0)
            idx = ((size_t)((h * 8 + b) * 1024 + s)) * 64 + kk;
          else
            idx = ((size_t)((h * 8 + b) * 64 + kk)) * 1024 + s;
          ((bf16_t*)out_)[idx] = (bf16_t)(v * scale);
        }
      }
}

// Flash attention v4. qh (PRE-SCALED by 1/8): [h][b][s][dk], kh: [h][b][s][dk],
// vt: [h][b][dk][s], c out: [b][s][h*64+dk].
// Block: 64 q-rows for one (h,b). 4 waves, each owns 16 q-rows.
// v4 changes (chain-shortening; v3 showed serial-latency bound, not occupancy/BW):
//  - Q fragments in registers (loop-invariant) -> sQ dropped.
//  - K double-buffered via register prefetch: next tile's global loads issued at
//    tile top (latency hidden under full tile), ds_write after PV, ONE barrier/tile.
//  - V loads issued BEFORE softmax (T14 issue-early): L2 latency hides under exp chain.
__global__ void attn_kernel(const bf16_t* __restrict__ qh, const bf16_t* __restrict__ kh,
                            const bf16_t* __restrict__ vt, bf16_t* __restrict__ c) {
  constexpr int KP = 72, PP = 72;
  __shared__ bf16_t sK[2][64 * KP];
  __shared__ bf16_t sP[4][16 * PP];
  const int t = threadIdx.x;
  const int w = t >> 6, l = t & 63;
  const int lq = l >> 4, ll = l & 15;
  // T1 swizzle: orig = x + 16*y, wg = (orig%8)*256 + orig/8 (bijective, 2048%8==0).
  const int orig = blockIdx.x + (blockIdx.y << 4);
  const int wg = (orig & 7) * 256 + (orig >> 3);
  const int q0 = (wg & 15) * 64;
  const int hb = wg >> 4;             // h*8+b
  const int h = hb >> 3, b = hb & 7;
  const size_t base = (size_t)hb * 65536;
  const bf16_t* Q = qh + base + (size_t)q0 * 64;
  const bf16_t* K = kh + base;
  const bf16_t* V = vt + base;        // [64][1024]

  // Q fragment straight from global, loop-invariant (one 16B load x2 per lane).
  bf16x8 aq[2];
#pragma unroll
  for (int ks = 0; ks < 2; ++ks)
    aq[ks] = *(const bf16x8*)(Q + (w * 16 + ll) * 64 + ks * 32 + lq * 8);

  // Prologue: stage K tile 0 into sK[0].
  uint4 kreg[2];
#pragma unroll
  for (int r = 0; r < 2; ++r) {
    int e = (r * 256 + t) * 8;
    kreg[r] = *(const uint4*)(K + e);
  }
#pragma unroll
  for (int r = 0; r < 2; ++r) {
    int e = (r * 256 + t) * 8;
    int row = e >> 6, col = e & 63;
    *(uint4*)(sK[0] + row * KP + col) = kreg[r];
  }
  __syncthreads();

  float mrow[4], lrow[4];
  f32x4 o[4] = {};
#pragma unroll
  for (int r = 0; r < 4; ++r) { mrow[r] = -1e30f; lrow[r] = 0.f; }

  int cur = 0;
  for (int kt = 0; kt < 1024; kt += 64, cur ^= 1) {
    // Prefetch next K tile into regs (consumed at ds_write after PV).
    if (kt + 64 < 1024) {
#pragma unroll
      for (int r = 0; r < 2; ++r) {
        int e = (r * 256 + t) * 8;
        kreg[r] = *(const uint4*)(K + (size_t)(kt + 64) * 64 + e);
      }
    }
    // Issue V loads for THIS tile now (consumed in PV, after softmax).
    bf16x8 bv[2][4];
#pragma unroll
    for (int ks = 0; ks < 2; ++ks)
#pragma unroll
      for (int ni = 0; ni < 4; ++ni)
        bv[ks][ni] = *(const bf16x8*)(V + (size_t)(ni * 16 + ll) * 1024 + kt + ks * 32 + lq * 8);
    // QK^T: S[q=lq*4+r (+w*16)][key=16ni+ll]
    f32x4 sacc[4] = {};
#pragma unroll
    for (int ni = 0; ni < 4; ++ni)
#pragma unroll
      for (int ks = 0; ks < 2; ++ks) {
        bf16x8 bk = *(const bf16x8*)(sK[cur] + (ni * 16 + ll) * KP + ks * 32 + lq * 8);
        sacc[ni] = MFMA(aq[ks], bk, sacc[ni]);
      }
    // Lane-partial max (Q pre-scaled). Full row max only needed on rescale.
    float rmax[4] = {-1e30f, -1e30f, -1e30f, -1e30f};
#pragma unroll
    for (int ni = 0; ni < 4; ++ni)
#pragma unroll
      for (int r = 0; r < 4; ++r)
        rmax[r] = fmaxf(rmax[r], sacc[ni][r]);
    // T13 defer-max: per-lane check; __all covers the 16 lanes of each row.
    bool ok = true;
#pragma unroll
    for (int r = 0; r < 4; ++r)
      ok = ok && (rmax[r] <= mrow[r] + 8.0f);
    if (!__all(ok)) {
      // Rare: true row max via shuffle, rescale lane-partial lrow + o.
#pragma unroll
      for (int off = 1; off < 16; off <<= 1)
#pragma unroll
        for (int r = 0; r < 4; ++r)
          rmax[r] = fmaxf(rmax[r], __shfl_xor(rmax[r], off));
#pragma unroll
      for (int r = 0; r < 4; ++r) {
        float mnew = fmaxf(mrow[r], rmax[r]);
        float alpha = __expf(mrow[r] - mnew);  // row-uniform: partials scale OK
        mrow[r] = mnew;
        lrow[r] *= alpha;
#pragma unroll
        for (int ni = 0; ni < 4; ++ni)
          o[ni][r] *= alpha;
      }
    }
    // P = exp(S - m); accumulate lane-partial row sums (no shuffles).
#pragma unroll
    for (int ni = 0; ni < 4; ++ni)
#pragma unroll
      for (int r = 0; r < 4; ++r) {
        float p = __expf(sacc[ni][r] - mrow[r]);
        sacc[ni][r] = p;
        lrow[r] += p;
      }
    // P -> LDS (per-wave buffer, wave-local ordering via lgkmcnt only).
    bf16_t* Pw = sP[w];
#pragma unroll
    for (int ni = 0; ni < 4; ++ni)
#pragma unroll
      for (int r = 0; r < 4; ++r)
        Pw[(lq * 4 + r) * PP + ni * 16 + ll] = (bf16_t)sacc[ni][r];
    asm volatile("s_waitcnt lgkmcnt(0)" ::: "memory");
    // PV: V already in registers (loads issued before softmax).
#pragma unroll
    for (int ks = 0; ks < 2; ++ks) {
      bf16x8 ap = *(const bf16x8*)(Pw + ll * PP + ks * 32 + lq * 8);
#pragma unroll
      for (int ni = 0; ni < 4; ++ni)
        o[ni] = MFMA(ap, bv[ks][ni], o[ni]);
    }
    // Stage next K tile into the alternate buffer; one barrier per tile.
    if (kt + 64 < 1024) {
#pragma unroll
      for (int r = 0; r < 2; ++r) {
        int e = (r * 256 + t) * 8;
        int row = e >> 6, col = e & 63;
        *(uint4*)(sK[cur ^ 1] + row * KP + col) = kreg[r];
      }
    }
    __syncthreads();
  }
  // Final: reduce lane-partial lrow across the 16 lanes of each row group.
#pragma unroll
  for (int off = 1; off < 16; off <<= 1)
#pragma unroll
    for (int r = 0; r < 4; ++r)
      lrow[r] += __shfl_xor(lrow[r], off);
#pragma unroll
  for (int ni = 0; ni < 4; ++ni)
#pragma unroll
    for (int r = 0; r < 4; ++r) {
      int s = q0 + w * 16 + lq * 4 + r;
      int dk = ni * 16 + ll;
      float val = o[ni][r] / lrow[r];
      c[((size_t)(b * 1024 + s)) * 1024 + h * 64 + dk] = (bf16_t)val;
    }
}

extern "C" void kernel_launch(void* const* d_in, const int* in_sizes, int n_in,
                              void* d_out, int out_size, void* d_ws, size_t ws_size,
                              hipStream_t stream) {
  float* out = (float*)d_out;   // reference output dtype is fp32!
  int nblk_out = (out_size + 255) / 256;
  if (n_in != 8) {
    fill_sentinel<<<nblk_out, 256, 0, stream>>>(out, out_size, 600.0f + 10.0f * n_in);
    return;
  }
  const int expect[8] = {8388608, 8388608, 8388608, 1048576,
                         1048576, 1048576, 1048576, 1024};
  for (int i = 0; i < 8; ++i)
    if (in_sizes[i] != expect[i]) {
      fill_sentinel<<<nblk_out, 256, 0, stream>>>(out, out_size, 500.0f + 10.0f * i);
      return;
    }

  // ws map (bf16 elems): qh [0,8M) | kh [8M,16M) | vt [16M,24M) | Wt/cbuf [24M,32M)
  bf16_t* ws   = (bf16_t*)d_ws;
  bf16_t* qhb  = ws;
  bf16_t* khb  = ws + 8388608;
  bf16_t* vtb  = ws + 16777216;
  bf16_t* Wt   = ws + 25165824;
  bf16_t* cbuf = ws + 25165824;   // overlaps Wt (dead after projections)
  bf16_t* Wob  = ws;              // overlaps qhb (dead after attn)
  if (ws_size < 67108864ull) {
    fill_sentinel<<<nblk_out, 256, 0, stream>>>(out, out_size, 400.0f);
    return;
  }

  const float* q  = (const float*)d_in[0];
  const float* k  = (const float*)d_in[1];
  const float* v  = (const float*)d_in[2];
  const float* Wq = (const float*)d_in[3];
  const float* Wk = (const float*)d_in[4];
  const float* Wv = (const float*)d_in[5];
  const float* Wo = (const float*)d_in[6];
  const float* bo = (const float*)d_in[7];

  // d_out (32MB) doubles as bf16 scratch until the final GEMM:
  //   qb [0,8M elems) , kb [8M,16M) ; vb reuses [0,8M) once qb is consumed.
  bf16_t* qb = (bf16_t*)d_out;
  bf16_t* kb = (bf16_t*)d_out + 8388608;
  bf16_t* vb = (bf16_t*)d_out;

  transpose_w<<<1536, 256, 0, stream>>>(Wq, Wk, Wv, Wt);
  cvt_bf16<<<4096, 256, 0, stream>>>(q, qb);
  cvt_bf16<<<4096, 256, 0, stream>>>(k, kb);
  dim3 gg(64, 8);
  // Q projection pre-scaled by 1/sqrt(d_k)=0.125 (exact pow2 in bf16).
  gemm_bt<0><<<gg, 256, 0, stream>>>(qb, Wt,           nullptr, qhb, 8192, 1024, 1024, 0.125f);
  gemm_bt<0><<<gg, 256, 0, stream>>>(kb, Wt + 1048576, nullptr, khb, 8192, 1024, 1024, 1.0f);
  cvt_bf16<<<4096, 256, 0, stream>>>(v, vb);
  gemm_bt<1><<<gg, 256, 0, stream>>>(vb, Wt + 2097152, nullptr, vtb, 8192, 1024, 1024, 1.0f);
  attn_kernel<<<dim3(16, 128), 256, 0, stream>>>(qhb, khb, vtb, cbuf);
  cvt_bf16<<<512, 256, 0, stream>>>(Wo, Wob);
  gemm_bt<2><<<gg, 256, 0, stream>>>(cbuf, Wob, bo, out, 8192, 1024, 1024, 1.0f);
}

// Round 5
// 410.020 us; speedup vs baseline: 1.1021x; 1.1021x over previous
//
#include <hip/hip_runtime.h>
#include <hip/hip_bf16.h>

typedef __bf16 bf16_t;
typedef __attribute__((ext_vector_type(8))) __bf16 bf16x8;
typedef __attribute__((ext_vector_type(4))) float f32x4;

#define MFMA(a, b, c) __builtin_amdgcn_mfma_f32_16x16x32_bf16(a, b, c, 0, 0, 0)

// Async global->LDS, 16B per lane. Dest = wave-uniform base + lane*16 (measured m104).
__device__ inline void gload_lds16(const bf16_t* g, bf16_t* l) {
  __builtin_amdgcn_global_load_lds(
      (const __attribute__((address_space(1))) void*)g,
      (__attribute__((address_space(3))) void*)l, 16, 0, 0);
}

// Diagnostic sentinel (fp32 output): absmax ~= val identifies the guard.
__global__ void fill_sentinel(float* out, int n, float val) {
  int i = blockIdx.x * blockDim.x + threadIdx.x;
  if (i < n) out[i] = val;
}

// Weights fp32 W[h][d][kk] (3 matrices) -> Wt bf16 [m][(h*64+kk)][d]
__global__ void transpose_w(const float* __restrict__ Wq, const float* __restrict__ Wk,
                            const float* __restrict__ Wv, bf16_t* __restrict__ Wt) {
  int gid = blockIdx.x * blockDim.x + threadIdx.x;
  int e = gid * 8;
  int m = e >> 20;
  int rem = e & 1048575;
  int n = rem >> 10;               // h*64+kk
  int d0 = rem & 1023;
  const float* W = (m == 0) ? Wq : (m == 1) ? Wk : Wv;
  int h = n >> 6, kk = n & 63;
  union { bf16_t h8[8]; uint4 u; } tmp;
#pragma unroll
  for (int j = 0; j < 8; ++j)
    tmp.h8[j] = (bf16_t)W[((size_t)(h * 1024 + d0 + j)) * 64 + kk];
  *(uint4*)(Wt + e) = tmp.u;
}

// Vectorized fp32 -> bf16 cast, 8 elems/thread, exact grid (no bounds check).
__global__ void cvt_bf16(const float* __restrict__ in, bf16_t* __restrict__ out) {
  size_t i = (size_t)(blockIdx.x * blockDim.x + threadIdx.x) * 8;
  f32x4 a = *(const f32x4*)(in + i);
  f32x4 b = *(const f32x4*)(in + i + 4);
  bf16x8 r;
  r[0] = (bf16_t)a[0]; r[1] = (bf16_t)a[1]; r[2] = (bf16_t)a[2]; r[3] = (bf16_t)a[3];
  r[4] = (bf16_t)b[0]; r[5] = (bf16_t)b[1]; r[6] = (bf16_t)b[2]; r[7] = (bf16_t)b[3];
  *(bf16x8*)(out + i) = r;
}

// C = A[M,K] * Bt[N,K]^T, all-bf16 inputs, m97-style global_load_lds staging.
// MODE 0: out bf16 [h][b][s][dk]; MODE 1: out bf16 [h][b][dk][s];
// MODE 2: out fp32 [M,N] + bias.  scale applied in MODE 0/1 epilogue.
template <int MODE>
__global__ void gemm_bt(const bf16_t* __restrict__ A, const bf16_t* __restrict__ Bt,
                        const float* __restrict__ bias, void* __restrict__ out_,
                        int M, int N, int K, float scale) {
  // Linear LDS (global_load_lds requires contiguous dest): [128 rows][32 elems].
  __shared__ bf16_t sA[128 * 32];
  __shared__ bf16_t sB[128 * 32];
  const int t = threadIdx.x;
  const int w = t >> 6, l = t & 63;
  const int lq = l >> 4, ll = l & 15;
  const int m0 = blockIdx.x * 128, n0 = blockIdx.y * 128;
  const int wr = (w >> 1) * 64, wc = (w & 1) * 64;
  // Staging: chunk ch = w*2+c covers rows [ch*16, ch*16+16); lane l lands at
  // chunk_base + l*16B -> row = ch*16 + l/4, col = (l&3)*8 elems.
  const int srow = l >> 2;
  const int scol = (l & 3) * 8;
  f32x4 acc[4][4] = {};
  for (int k0 = 0; k0 < K; k0 += 32) {
    __syncthreads();   // prior ds_reads done before overwrite
#pragma unroll
    for (int c = 0; c < 2; ++c) {
      int ch = w * 2 + c;
      int row = ch * 16 + srow;
      gload_lds16(A  + (size_t)(m0 + row) * K + k0 + scol, sA + ch * 512);
      gload_lds16(Bt + (size_t)(n0 + row) * K + k0 + scol, sB + ch * 512);
    }
    __syncthreads();   // implicit vmcnt(0) drains global_load_lds
    bf16x8 af[4], bfr[4];
#pragma unroll
    for (int i = 0; i < 4; ++i) {
      af[i]  = *(const bf16x8*)(sA + (wr + i * 16 + ll) * 32 + lq * 8);
      bfr[i] = *(const bf16x8*)(sB + (wc + i * 16 + ll) * 32 + lq * 8);
    }
#pragma unroll
    for (int mi = 0; mi < 4; ++mi)
#pragma unroll
      for (int ni = 0; ni < 4; ++ni)
        acc[mi][ni] = MFMA(af[mi], bfr[ni], acc[mi][ni]);
  }
  // D layout: col=lane&15, row=(lane>>4)*4+reg (measured m89/m91).
#pragma unroll
  for (int mi = 0; mi < 4; ++mi)
#pragma unroll
    for (int ni = 0; ni < 4; ++ni)
#pragma unroll
      for (int r = 0; r < 4; ++r) {
        int row = m0 + wr + mi * 16 + lq * 4 + r;
        int col = n0 + wc + ni * 16 + ll;
        float v = acc[mi][ni][r];
        if (MODE == 2) {
          ((float*)out_)[(size_t)row * N + col] = v + bias[col];
        } else {
          int h = col >> 6, kk = col & 63, b = row >> 10, s = row & 1023;
          size_t idx;
          if (MODE == 0)
            idx = ((size_t)((h * 8 + b) * 1024 + s)) * 64 + kk;
          else
            idx = ((size_t)((h * 8 + b) * 64 + kk)) * 1024 + s;
          ((bf16_t*)out_)[idx] = (bf16_t)(v * scale);
        }
      }
}

// Flash attention v5. qh (PRE-SCALED by 1/8): [h][b][s][dk], kh: [h][b][s][dk],
// vt: [h][b][dk][s], c out: [b][s][h*64+dk].
// Block: 64 q-rows for one (h,b). 4 waves, each owns 16 q-rows.
// v5 = v3 skeleton + swapped QK^T (S^T = MFMA(K,Q); A/B frag layouts are identical
// for 16x16x32 so loads are unchanged). Lane holds q = w*16+ll fixed, keys =
// ni*16+lq*4+r -> scalar per-lane m/l state, P-write packed as 4x ds_write_b64.
// K double-buffered via NAMED uint4 regs (v4's bv[2][4] array got LDS-demoted:
// LDS 27648->60416; named scalars prevent that), ONE barrier/tile.
// V loads as 8 named bf16x8, issued before softmax (L2 latency hides under exp).
__global__ void attn_kernel(const bf16_t* __restrict__ qh, const bf16_t* __restrict__ kh,
                            const bf16_t* __restrict__ vt, bf16_t* __restrict__ c) {
  constexpr int KP = 72, PP = 72;
  __shared__ bf16_t sK[2][64 * KP];
  __shared__ bf16_t sP[4][16 * PP];
  const int t = threadIdx.x;
  const int w = t >> 6, l = t & 63;
  const int lq = l >> 4, ll = l & 15;
  // T1 swizzle: orig = x + 16*y, wg = (orig%8)*256 + orig/8 (bijective, 2048%8==0).
  const int orig = blockIdx.x + (blockIdx.y << 4);
  const int wg = (orig & 7) * 256 + (orig >> 3);
  const int q0 = (wg & 15) * 64;
  const int hb = wg >> 4;             // h*8+b
  const int h = hb >> 3, b = hb & 7;
  const size_t base = (size_t)hb * 65536;
  const bf16_t* Q = qh + base + (size_t)q0 * 64;
  const bf16_t* K = kh + base;
  const bf16_t* V = vt + base;        // [64][1024]

  // Q fragments loop-invariant in regs (B-operand of swapped QK: col=q=ll).
  bf16x8 aq0 = *(const bf16x8*)(Q + (w * 16 + ll) * 64 + 0 * 32 + lq * 8);
  bf16x8 aq1 = *(const bf16x8*)(Q + (w * 16 + ll) * 64 + 1 * 32 + lq * 8);

  // Prologue: stage K tile 0 into sK[0].
  {
    int e0 = t * 8, e1 = (256 + t) * 8;
    uint4 ka = *(const uint4*)(K + e0);
    uint4 kb = *(const uint4*)(K + e1);
    *(uint4*)(sK[0] + (e0 >> 6) * KP + (e0 & 63)) = ka;
    *(uint4*)(sK[0] + (e1 >> 6) * KP + (e1 & 63)) = kb;
  }
  __syncthreads();

  float mrow = -1e30f, lrow = 0.f;    // per-lane state for q = w*16+ll
  f32x4 o[4] = {};
  bf16_t* Pw = sP[w];

  int cur = 0;
  for (int kt = 0; kt < 1024; kt += 64, cur ^= 1) {
    // Prefetch next K tile into named regs (ds_write after PV, before barrier).
    uint4 kr0, kr1;
    if (kt < 960) {
      kr0 = *(const uint4*)(K + (size_t)(kt + 64) * 64 + t * 8);
      kr1 = *(const uint4*)(K + (size_t)(kt + 64) * 64 + (256 + t) * 8);
    }
    // V loads for THIS tile, named (prevents LDS demotion). B-frag: col=dk, k=key.
    const bf16_t* Vb = V + (size_t)ll * 1024 + kt + lq * 8;
    bf16x8 bv00 = *(const bf16x8*)(Vb + 0 * 16384 + 0);
    bf16x8 bv01 = *(const bf16x8*)(Vb + 1 * 16384 + 0);
    bf16x8 bv02 = *(const bf16x8*)(Vb + 2 * 16384 + 0);
    bf16x8 bv03 = *(const bf16x8*)(Vb + 3 * 16384 + 0);
    bf16x8 bv10 = *(const bf16x8*)(Vb + 0 * 16384 + 32);
    bf16x8 bv11 = *(const bf16x8*)(Vb + 1 * 16384 + 32);
    bf16x8 bv12 = *(const bf16x8*)(Vb + 2 * 16384 + 32);
    bf16x8 bv13 = *(const bf16x8*)(Vb + 3 * 16384 + 32);

    // Swapped QK^T: S^T[key][q] = MFMA(K-frag, Q-frag). Same LDS addresses as v3.
    f32x4 sacc[4] = {};
    __builtin_amdgcn_s_setprio(1);
#pragma unroll
    for (int ni = 0; ni < 4; ++ni) {
      bf16x8 bk0 = *(const bf16x8*)(sK[cur] + (ni * 16 + ll) * KP + 0 * 32 + lq * 8);
      bf16x8 bk1 = *(const bf16x8*)(sK[cur] + (ni * 16 + ll) * KP + 1 * 32 + lq * 8);
      sacc[ni] = MFMA(bk0, aq0, sacc[ni]);
      sacc[ni] = MFMA(bk1, aq1, sacc[ni]);
    }
    __builtin_amdgcn_s_setprio(0);
    // Lane-partial max over this lane's 16 keys (all for q = w*16+ll).
    float rmax = -1e30f;
#pragma unroll
    for (int ni = 0; ni < 4; ++ni)
#pragma unroll
      for (int r = 0; r < 4; ++r)
        rmax = fmaxf(rmax, sacc[ni][r]);
    // T13 defer-max: rare rescale only when max grows past THR=8.
    if (!__all(rmax <= mrow + 8.0f)) {
      // True row max: combine the 4 lq-group partials (lanes +-16, +-32).
      rmax = fmaxf(rmax, __shfl_xor(rmax, 16));
      rmax = fmaxf(rmax, __shfl_xor(rmax, 32));
      float mnew = fmaxf(mrow, rmax);
      float alpha = __expf(mrow - mnew);
      mrow = mnew;
      lrow *= alpha;
      // o rows are q = lq*4+r; alpha lives at lane q (per 16-lane segment).
#pragma unroll
      for (int r = 0; r < 4; ++r) {
        float ar = __shfl(alpha, lq * 4 + r, 16);
#pragma unroll
        for (int ni = 0; ni < 4; ++ni)
          o[ni][r] *= ar;
      }
    }
    // P = exp(S - m); lane-partial row sum (scalar, no shuffles).
#pragma unroll
    for (int ni = 0; ni < 4; ++ni)
#pragma unroll
      for (int r = 0; r < 4; ++r) {
        float p = __expf(sacc[ni][r] - mrow);
        sacc[ni][r] = p;
        lrow += p;
      }
    // P-write: consecutive r = consecutive keys -> one 8B packed write per ni.
    // Pw[q=ll][key = ni*16 + lq*4 + r].
#pragma unroll
    for (int ni = 0; ni < 4; ++ni) {
      union { bf16_t h4[4]; uint2 u; } pk;
      pk.h4[0] = (bf16_t)sacc[ni][0];
      pk.h4[1] = (bf16_t)sacc[ni][1];
      pk.h4[2] = (bf16_t)sacc[ni][2];
      pk.h4[3] = (bf16_t)sacc[ni][3];
      *(uint2*)(Pw + ll * PP + ni * 16 + lq * 4) = pk.u;
    }
    asm volatile("s_waitcnt lgkmcnt(0)" ::: "memory");
    __builtin_amdgcn_sched_barrier(0);   // rule #18: block MFMA hoist past the wait
    // PV: A = P[q=ll][keys lq*8..+7] (16B ds_read), B = V (regs, issued early).
    bf16x8 ap0 = *(const bf16x8*)(Pw + ll * PP + 0 * 32 + lq * 8);
    bf16x8 ap1 = *(const bf16x8*)(Pw + ll * PP + 1 * 32 + lq * 8);
    __builtin_amdgcn_s_setprio(1);
    o[0] = MFMA(ap0, bv00, o[0]);
    o[1] = MFMA(ap0, bv01, o[1]);
    o[2] = MFMA(ap0, bv02, o[2]);
    o[3] = MFMA(ap0, bv03, o[3]);
    o[0] = MFMA(ap1, bv10, o[0]);
    o[1] = MFMA(ap1, bv11, o[1]);
    o[2] = MFMA(ap1, bv12, o[2]);
    o[3] = MFMA(ap1, bv13, o[3]);
    __builtin_amdgcn_s_setprio(0);
    // Stage next K tile into alternate buffer; ONE barrier per tile.
    if (kt < 960) {
      int e0 = t * 8, e1 = (256 + t) * 8;
      *(uint4*)(sK[cur ^ 1] + (e0 >> 6) * KP + (e0 & 63)) = kr0;
      *(uint4*)(sK[cur ^ 1] + (e1 >> 6) * KP + (e1 & 63)) = kr1;
    }
    __syncthreads();
  }
  // Final: true lrow(q=ll) = sum of 4 lq-group partials; map to o's q = lq*4+r.
  lrow += __shfl_xor(lrow, 16);
  lrow += __shfl_xor(lrow, 32);
#pragma unroll
  for (int r = 0; r < 4; ++r) {
    float lr = __shfl(lrow, lq * 4 + r, 16);
    int s = q0 + w * 16 + lq * 4 + r;
#pragma unroll
    for (int ni = 0; ni < 4; ++ni) {
      int dk = ni * 16 + ll;
      c[((size_t)(b * 1024 + s)) * 1024 + h * 64 + dk] = (bf16_t)(o[ni][r] / lr);
    }
  }
}

extern "C" void kernel_launch(void* const* d_in, const int* in_sizes, int n_in,
                              void* d_out, int out_size, void* d_ws, size_t ws_size,
                              hipStream_t stream) {
  float* out = (float*)d_out;   // reference output dtype is fp32!
  int nblk_out = (out_size + 255) / 256;
  if (n_in != 8) {
    fill_sentinel<<<nblk_out, 256, 0, stream>>>(out, out_size, 600.0f + 10.0f * n_in);
    return;
  }
  const int expect[8] = {8388608, 8388608, 8388608, 1048576,
                         1048576, 1048576, 1048576, 1024};
  for (int i = 0; i < 8; ++i)
    if (in_sizes[i] != expect[i]) {
      fill_sentinel<<<nblk_out, 256, 0, stream>>>(out, out_size, 500.0f + 10.0f * i);
      return;
    }

  // ws map (bf16 elems): qh [0,8M) | kh [8M,16M) | vt [16M,24M) | Wt/cbuf [24M,32M)
  bf16_t* ws   = (bf16_t*)d_ws;
  bf16_t* qhb  = ws;
  bf16_t* khb  = ws + 8388608;
  bf16_t* vtb  = ws + 16777216;
  bf16_t* Wt   = ws + 25165824;
  bf16_t* cbuf = ws + 25165824;   // overlaps Wt (dead after projections)
  bf16_t* Wob  = ws;              // overlaps qhb (dead after attn)
  if (ws_size < 67108864ull) {
    fill_sentinel<<<nblk_out, 256, 0, stream>>>(out, out_size, 400.0f);
    return;
  }

  const float* q  = (const float*)d_in[0];
  const float* k  = (const float*)d_in[1];
  const float* v  = (const float*)d_in[2];
  const float* Wq = (const float*)d_in[3];
  const float* Wk = (const float*)d_in[4];
  const float* Wv = (const float*)d_in[5];
  const float* Wo = (const float*)d_in[6];
  const float* bo = (const float*)d_in[7];

  // d_out (32MB) doubles as bf16 scratch until the final GEMM:
  //   qb [0,8M elems) , kb [8M,16M) ; vb reuses [0,8M) once qb is consumed.
  bf16_t* qb = (bf16_t*)d_out;
  bf16_t* kb = (bf16_t*)d_out + 8388608;
  bf16_t* vb = (bf16_t*)d_out;

  transpose_w<<<1536, 256, 0, stream>>>(Wq, Wk, Wv, Wt);
  cvt_bf16<<<4096, 256, 0, stream>>>(q, qb);
  cvt_bf16<<<4096, 256, 0, stream>>>(k, kb);
  dim3 gg(64, 8);
  // Q projection pre-scaled by 1/sqrt(d_k)=0.125 (exact pow2 in bf16).
  gemm_bt<0><<<gg, 256, 0, stream>>>(qb, Wt,           nullptr, qhb, 8192, 1024, 1024, 0.125f);
  gemm_bt<0><<<gg, 256, 0, stream>>>(kb, Wt + 1048576, nullptr, khb, 8192, 1024, 1024, 1.0f);
  cvt_bf16<<<4096, 256, 0, stream>>>(v, vb);
  gemm_bt<1><<<gg, 256, 0, stream>>>(vb, Wt + 2097152, nullptr, vtb, 8192, 1024, 1024, 1.0f);
  attn_kernel<<<dim3(16, 128), 256, 0, stream>>>(qhb, khb, vtb, cbuf);
  cvt_bf16<<<512, 256, 0, stream>>>(Wo, Wob);
  gemm_bt<2><<<gg, 256, 0, stream>>>(cbuf, Wob, bo, out, 8192, 1024, 1024, 1.0f);
}